// Round 9
// baseline (2635.450 us; speedup 1.0000x reference)
//
#include <hip/hip_runtime.h>

#define BB 8
#define NN 8192
#define MM 2048
#define KK 32
#define NTOT (BB*MM*KK)   // 524288

// ws layout (float offsets)
#define WS_PTS_T  0          // 4,194,304 f  (B,N,64)
#define WS_XYZN   4194304    // 1,048,576 f  (B,N) float4
#define WS_IDX    5242880    //   524,288 i  (B,M,32)
#define WS_GPART  5767168    //   524,288 f  [s*128+o][2048]
#define WS_PARAMS 6291456    //     1,024 f  layer*256 + {A[0..127], C[128..255]}
#define WS_ZMAX   6292480    // 2,097,152 f
#define WS_ZMIN   8389632    // 2,097,152 f
#define WS_TOTAL  10486784

typedef float v2f __attribute__((ext_vector_type(2)));

// ---------------- transpose points (B,64,N) -> (B,N,64) ----------------
__global__ __launch_bounds__(256) void k_transpose(const float* __restrict__ pts,
                                                   float* __restrict__ pts_t){
  __shared__ float tile[64][65];
  int bid = blockIdx.x;
  int b = bid >> 7;                 // 128 tiles per batch
  int n0 = (bid & 127) << 6;
  int tx = threadIdx.x & 63, ty = threadIdx.x >> 6;
  const float* src = pts + (size_t)b*64*NN;
  #pragma unroll
  for (int c = ty; c < 64; c += 4)
    tile[c][tx] = src[(size_t)c*NN + n0 + tx];
  __syncthreads();
  float* dst = pts_t + ((size_t)b*NN + n0)*64;
  #pragma unroll
  for (int r = ty; r < 64; r += 4)
    dst[(size_t)r*64 + tx] = tile[tx][r];
}

// ---------------- xyz + norm staging (B,N) float4 ----------------
__global__ __launch_bounds__(256) void k_xyzn(const float* __restrict__ xyz,
                                              float4* __restrict__ xyzn){
  #pragma clang fp contract(off)
  int i = blockIdx.x*256 + threadIdx.x;   // 65536
  int b = i >> 13, n = i & 8191;
  const float* p = xyz + (size_t)b*3*NN;
  float x = p[n], y = p[NN+n], z = p[2*NN+n];
  float nrm = (x*x + y*y) + z*z;
  xyzn[i] = make_float4(x, y, z, nrm);
}

// ---------------- farthest point sampling ----------------
// 256 threads (4 waves, 1/SIMD), 32 contiguous points/thread, LDS mirror.
// r9: serial-chain-bound -> tree-max for bv (depth 5 vs 16) and tree-min
// index select (depth 5 vs 32 dependent cndmasks). Selection identical:
// min over matching indices == first match in descending scan.
#define DPPMAXF(ctrl, rmask)                                                 \
  {                                                                          \
    float s_ = __int_as_float(__builtin_amdgcn_update_dpp(                   \
        __float_as_int(m), __float_as_int(m), (ctrl), (rmask), 0xf, false)); \
    m = fmaxf(m, s_);                                                        \
  }

__global__ __launch_bounds__(256,1) void k_fps(const float* __restrict__ xyz,
                                               float* __restrict__ out_newxyz){
  #pragma clang fp contract(off)
  __shared__ float4 sp4[NN];                     // 128 KB
  __shared__ unsigned long long swk[2][4];
  int b = blockIdx.x, tid = threadIdx.x;
  const float* xb = xyz + (size_t)b*3*NN;
  int n0 = tid << 5;                             // 32 contiguous points
  v2f px[16], py[16], pz[16], dd[16];
  const float4* xb4 = (const float4*)xb;
  #pragma unroll
  for (int q = 0; q < 8; ++q){
    float4 X = xb4[(n0>>2) + q];
    float4 Y = xb4[(NN>>2) + (n0>>2) + q];
    float4 Z = xb4[((2*NN)>>2) + (n0>>2) + q];
    px[2*q]   = (v2f){X.x, X.y}; px[2*q+1] = (v2f){X.z, X.w};
    py[2*q]   = (v2f){Y.x, Y.y}; py[2*q+1] = (v2f){Y.z, Y.w};
    pz[2*q]   = (v2f){Z.x, Z.y}; pz[2*q+1] = (v2f){Z.z, Z.w};
    dd[2*q]   = (v2f){1e10f,1e10f}; dd[2*q+1] = (v2f){1e10f,1e10f};
    sp4[n0+4*q+0] = make_float4(X.x, Y.x, Z.x, 0.f);
    sp4[n0+4*q+1] = make_float4(X.y, Y.y, Z.y, 0.f);
    sp4[n0+4*q+2] = make_float4(X.z, Y.z, Z.z, 0.f);
    sp4[n0+4*q+3] = make_float4(X.w, Y.w, Z.w, 0.f);
  }
  __syncthreads();
  float4 c0 = sp4[0];                            // far = 0 initially
  float cx = c0.x, cy = c0.y, cz = c0.z;
  float* ob = out_newxyz + (size_t)b*3*MM;
  int lane = tid & 63, wid = tid >> 6;
  const int JINF = 0x7fffffff;
  for (int s = 0; s < 8; ++s){
    float ox = 0.f, oy = 0.f, oz = 0.f;
    #pragma unroll 1
    for (int ti = 0; ti < 256; ++ti){
      if (tid == ti){ ox = cx; oy = cy; oz = cz; }   // register capture
      v2f cvx = (v2f){cx,cx}, cvy = (v2f){cy,cy}, cvz = (v2f){cz,cz};
      #pragma unroll
      for (int g = 0; g < 16; ++g){
        v2f dx = px[g]-cvx, dy = py[g]-cvy, dz = pz[g]-cvz;
        v2f xx = dx*dx, yy = dy*dy, zz = dz*dz;
        v2f sm = xx + yy;                           // linear sum order == np
        v2f d  = sm + zz;
        dd[g] = __builtin_elementwise_min(dd[g], d);
      }
      // tree max (depth 5, independent pairs)
      v2f t8[8], t4[4], t2[2], t1;
      #pragma unroll
      for (int g = 0; g < 8; ++g) t8[g] = __builtin_elementwise_max(dd[2*g], dd[2*g+1]);
      #pragma unroll
      for (int g = 0; g < 4; ++g) t4[g] = __builtin_elementwise_max(t8[2*g], t8[2*g+1]);
      t2[0] = __builtin_elementwise_max(t4[0], t4[1]);
      t2[1] = __builtin_elementwise_max(t4[2], t4[3]);
      t1 = __builtin_elementwise_max(t2[0], t2[1]);
      float bv = fmaxf(t1.x, t1.y);
      // wave max (f32, DPP); result valid in lane 63
      float m = bv;
      DPPMAXF(0x111, 0xf)   // row_shr:1
      DPPMAXF(0x112, 0xf)   // row_shr:2
      DPPMAXF(0x114, 0xf)   // row_shr:4
      DPPMAXF(0x118, 0xf)   // row_shr:8
      DPPMAXF(0x142, 0xa)   // row_bcast:15 -> rows 1,3
      DPPMAXF(0x143, 0xc)   // row_bcast:31 -> rows 2,3
      float wm = __int_as_float(__builtin_amdgcn_readlane(__float_as_int(m), 63));
      unsigned long long msk = __ballot(bv == wm);
      int wl = (int)__builtin_ctzll(msk);           // lowest lane among ties
      // tree-min index select (lowest j with dd==bv)
      int s16[16], s8[8], s4[4], s2[2];
      #pragma unroll
      for (int g = 0; g < 16; ++g){
        int j0 = (dd[g].x == bv) ? (2*g)   : JINF;
        int j1 = (dd[g].y == bv) ? (2*g+1) : JINF;
        s16[g] = min(j0, j1);
      }
      #pragma unroll
      for (int g = 0; g < 8; ++g) s8[g] = min(s16[2*g], s16[2*g+1]);
      #pragma unroll
      for (int g = 0; g < 4; ++g) s4[g] = min(s8[2*g], s8[2*g+1]);
      s2[0] = min(s4[0], s4[1]); s2[1] = min(s4[2], s4[3]);
      int bj = min(s2[0], s2[1]);
      int nwin = __builtin_amdgcn_readlane(n0 + bj, wl);
      int buf = ti & 1;
      if (lane == 0){
        unsigned long long key =
            ((unsigned long long)__float_as_uint(wm) << 32) |
            (unsigned int)(~(unsigned int)nwin);
        swk[buf][wid] = key;
      }
      __syncthreads();
      const unsigned long long* kk = swk[buf];
      unsigned long long k0=kk[0], k1=kk[1], k2=kk[2], k3=kk[3];
      unsigned long long a = (k0>k1)?k0:k1, c2 = (k2>k3)?k2:k3;
      unsigned long long kmax = (a>c2)?a:c2;
      int far = (int)(~(unsigned int)kmax) & (NN-1);
      float4 c4 = sp4[far];
      cx = c4.x; cy = c4.y; cz = c4.z;
    }
    ob[(s<<8)+tid] = ox; ob[MM+(s<<8)+tid] = oy; ob[2*MM+(s<<8)+tid] = oz;
  }
}

// ---------------- ball query: parallel mask build + serial emit ----------------
__global__ __launch_bounds__(256) void k_ballq(const float4* __restrict__ xyzn,
                                               const float* __restrict__ newxyz,
                                               int* __restrict__ idx){
  #pragma clang fp contract(off)
  __shared__ unsigned long long s_mask[32][129];   // padded: 2-way bank alias only
  __shared__ float4 s_c4[32];
  const float R2 = (float)(0.2*0.2);
  int b = blockIdx.x >> 6;                 // 64 blocks per batch
  int m0 = (blockIdx.x & 63) << 5;         // 32 centroids per block
  int tid = threadIdx.x, lane = tid & 63, wv = tid >> 6;
  const float* nb = newxyz + (size_t)b*3*MM;
  if (tid < 32){
    int m = m0 + tid;
    float cx = nb[m], cy = nb[MM+m], cz = nb[2*MM+m];
    float cn = (cx*cx + cy*cy) + cz*cz;
    s_c4[tid] = make_float4(cx, cy, cz, cn);
  }
  __syncthreads();
  const float4* src = xyzn + (size_t)b*NN;
  for (int ci = 0; ci < 32; ++ci){
    int ch = ci*4 + wv;
    float4 p = src[ch*64 + lane];
    #pragma unroll 8
    for (int mi = 0; mi < 32; ++mi){
      float4 c = s_c4[mi];
      float dot = (c.x*p.x + c.y*p.y) + c.z*p.z;   // linear, no fma (matches np)
      float sq = (c.w + p.w) - 2.0f*dot;
      unsigned long long mk = __ballot(sq < R2);
      if (lane == 0) s_mask[mi][ch] = mk;
    }
  }
  __syncthreads();
  if (tid < 32){
    int m = m0 + tid;
    int* om = idx + ((size_t)(b*MM + m))*KK;
    int filled = 0, first = -1;
    for (int ch = 0; ch < 128 && filled < KK; ++ch){
      unsigned long long mk = s_mask[tid][ch];
      while (mk){
        int bp = __builtin_ctzll(mk);
        mk &= mk - 1;
        int j = ch*64 + bp;
        if (first < 0) first = j;
        om[filled++] = j;
        if (filled == KK) break;
      }
    }
    int pad = (first < 0) ? 0 : first;
    for (int s = filled; s < KK; ++s) om[s] = pad;
  }
}

// ---------------- GEMM helpers (register-tiled convs, v_pk_fma) ----------------
#define XST 260   // X_lds row stride in floats; 1040 B, 16B-aligned
#define PST 66    // s_pp row stride (64 was a 32-way read conflict)

// one K-step: acc[8 outs][4 v2f = 8 pos] += w (x) x   (packed f32 fma)
__device__ __forceinline__ void gemm_step(v2f (&acc)[8][4], const float* sw,
                                          const float* sx, int c, int ob8, int pb){
  float4 X0 = *(const float4*)&sx[c*XST + pb];
  float4 X1 = *(const float4*)&sx[c*XST + pb + 4];
  v2f xv[4] = { (v2f){X0.x,X0.y}, (v2f){X0.z,X0.w},
                (v2f){X1.x,X1.y}, (v2f){X1.z,X1.w} };
  float4 W0 = *(const float4*)&sw[c*64 + ob8];
  float4 W1 = *(const float4*)&sw[c*64 + ob8 + 4];
  float ws[8] = {W0.x,W0.y,W0.z,W0.w,W1.x,W1.y,W1.z,W1.w};
  #pragma unroll
  for (int oi = 0; oi < 8; ++oi){
    v2f wv = (v2f){ws[oi], ws[oi]};
    #pragma unroll
    for (int p = 0; p < 4; ++p)
      acc[oi][p] = __builtin_elementwise_fma(wv, xv[p], acc[oi][p]);
  }
}

__device__ __forceinline__ void zero_acc(v2f (&acc)[8][4]){
  #pragma unroll
  for (int oi = 0; oi < 8; ++oi)
    #pragma unroll
    for (int p = 0; p < 4; ++p) acc[oi][p] = (v2f){0.f, 0.f};
}

// gather position tid's 67 inputs into column tid of X_lds (conflict-free)
__device__ __forceinline__ void gather_col(float* sx, const float* pts_t,
    const float4* xyzn, const float* nb, const int* idx, int b, int bid, int tid){
  int m0 = (bid & 255) << 3;
  int m = m0 + (tid >> 5), k = tid & 31;
  int j = idx[((size_t)(b*MM + m))*KK + k];
  float4 P = xyzn[(size_t)b*NN + j];
  sx[0*XST + tid] = P.x - nb[m];
  sx[1*XST + tid] = P.y - nb[MM+m];
  sx[2*XST + tid] = P.z - nb[2*MM+m];
  const float4* pf = (const float4*)(pts_t + ((size_t)b*NN + j)*64);
  #pragma unroll
  for (int c4 = 0; c4 < 16; ++c4){
    float4 v = pf[c4];
    sx[(3+4*c4+0)*XST + tid] = v.x;
    sx[(3+4*c4+1)*XST + tid] = v.y;
    sx[(3+4*c4+2)*XST + tid] = v.z;
    sx[(3+4*c4+3)*XST + tid] = v.w;
  }
}

// bn+relu on the v2f tile (packed fma+max; per-element math identical)
__device__ __forceinline__ void bnrelu_tile(v2f (&acc)[8][4], const float* sA,
                                            const float* sC, int ob8){
  v2f Z = (v2f){0.f, 0.f};
  #pragma unroll
  for (int oi = 0; oi < 8; ++oi){
    v2f Av = (v2f){sA[ob8+oi], sA[ob8+oi]};
    v2f Cv = (v2f){sC[ob8+oi], sC[ob8+oi]};
    #pragma unroll
    for (int p = 0; p < 4; ++p)
      acc[oi][p] = __builtin_elementwise_max(
          __builtin_elementwise_fma(Av, acc[oi][p], Cv), Z);
  }
}

__device__ __forceinline__ void stash_tile(const v2f (&acc)[8][4], float* sx,
                                           int ob8, int pb){
  #pragma unroll
  for (int oi = 0; oi < 8; ++oi){
    *(float4*)&sx[(ob8+oi)*XST + pb] =
        make_float4(acc[oi][0].x, acc[oi][0].y, acc[oi][1].x, acc[oi][1].y);
    *(float4*)&sx[(ob8+oi)*XST + pb + 4] =
        make_float4(acc[oi][2].x, acc[oi][2].y, acc[oi][3].x, acc[oi][3].y);
  }
}

// per-thread tile stats -> s_pp -> gpart (scalar order preserved exactly)
__device__ __forceinline__ void tile_stats(const v2f (&acc)[8][4], float* s_pp,
    float* gpart, int ob8, int pg, int tid, int bid, int nch_base){
  #pragma unroll
  for (int oi = 0; oi < 8; ++oi){
    float a0x=acc[oi][0].x, a0y=acc[oi][0].y, a0z=acc[oi][1].x, a0w=acc[oi][1].y;
    float a1x=acc[oi][2].x, a1y=acc[oi][2].y, a1z=acc[oi][3].x, a1w=acc[oi][3].y;
    float s  = ((a0x+a0y)+(a0z+a0w)) + ((a1x+a1y)+(a1z+a1w));
    float q2 = ((a0x*a0x + a0y*a0y) + (a0z*a0z + a0w*a0w))
             + ((a1x*a1x + a1y*a1y) + (a1z*a1z + a1w*a1w));
    int o = ob8 + oi;
    s_pp[o*PST + pg*2 + 0] = s;
    s_pp[o*PST + pg*2 + 1] = q2;
  }
  __syncthreads();
  if (tid < 128){
    int o = tid >> 1, st = tid & 1;
    float S = 0.f;
    #pragma unroll 8
    for (int q = 0; q < 32; ++q) S += s_pp[o*PST + q*2 + st];
    gpart[(size_t)(st*128 + nch_base + o)*2048 + bid] = S;
  }
}

// ---------------- K4: conv1 (GEMM) -> stats1 ----------------
__global__ __launch_bounds__(256,1) void k_conv1_stats(const float* __restrict__ pts_t,
    const float4* __restrict__ xyzn, const float* __restrict__ newxyz,
    const int* __restrict__ idx, const float* __restrict__ W1, float* __restrict__ gpart){
  __shared__ float s_w1[67*64];
  __shared__ float s_x[67*XST];               // also reused as s_pp
  int tid = threadIdx.x;
  for (int i = tid; i < 67*64; i += 256){ int c = i>>6, o = i&63; s_w1[i] = W1[o*67 + c]; }
  int bid = blockIdx.x, b = bid >> 8;
  const float* nb = newxyz + (size_t)b*3*MM;
  gather_col(s_x, pts_t, xyzn, nb, idx, b, bid, tid);
  __syncthreads();
  int oq = tid & 7, pg = tid >> 3;
  int ob8 = oq*8, pb = pg*8;
  v2f acc[8][4];
  zero_acc(acc);
  for (int c = 0; c < 67; ++c) gemm_step(acc, s_w1, s_x, c, ob8, pb);
  __syncthreads();                            // s_x dead -> reuse
  tile_stats(acc, s_x, gpart, ob8, pg, tid, bid, 0);
}

// ---------------- K5: conv1 -> bn1/relu -> conv2 (GEMM) -> stats2 ----------------
__global__ __launch_bounds__(256,1) void k_conv2_stats(const float* __restrict__ pts_t,
    const float4* __restrict__ xyzn, const float* __restrict__ newxyz,
    const int* __restrict__ idx, const float* __restrict__ W1, const float* __restrict__ W2,
    const float* __restrict__ params1, float* __restrict__ gpart){
  __shared__ float s_w1[67*64];
  __shared__ float s_w2[64*64];
  __shared__ float s_p[128];
  __shared__ float s_x[67*XST];               // X1, then h1 stash, then s_pp
  int tid = threadIdx.x;
  for (int i = tid; i < 67*64; i += 256){ int c = i>>6, o = i&63; s_w1[i] = W1[o*67 + c]; }
  for (int i = tid; i < 64*64; i += 256){ int c = i>>6, o = i&63; s_w2[i] = W2[o*64 + c]; }
  if (tid < 64){ s_p[tid] = params1[tid]; s_p[64+tid] = params1[128+tid]; }
  int bid = blockIdx.x, b = bid >> 8;
  const float* nb = newxyz + (size_t)b*3*MM;
  gather_col(s_x, pts_t, xyzn, nb, idx, b, bid, tid);
  __syncthreads();
  int oq = tid & 7, pg = tid >> 3;
  int ob8 = oq*8, pb = pg*8;
  v2f acc[8][4];
  zero_acc(acc);
  for (int c = 0; c < 67; ++c) gemm_step(acc, s_w1, s_x, c, ob8, pb);
  bnrelu_tile(acc, s_p, s_p+64, ob8);
  __syncthreads();                            // everyone done reading X1
  stash_tile(acc, s_x, ob8, pb);
  __syncthreads();
  zero_acc(acc);
  for (int c = 0; c < 64; ++c) gemm_step(acc, s_w2, s_x, c, ob8, pb);
  __syncthreads();                            // h1 dead -> reuse as s_pp
  tile_stats(acc, s_x, gpart, ob8, pg, tid, bid, 0);
}

// ---------------- BN finalize: deterministic f64 reduce ----------------
__global__ __launch_bounds__(256) void k_bnfin(const float* __restrict__ gpart,
    const float* __restrict__ g, const float* __restrict__ be, float* __restrict__ params){
  int o = blockIdx.x, t = threadIdx.x;
  double s = 0.0, sq = 0.0;
  for (int i = t; i < 2048; i += 256){
    s  += (double)gpart[(size_t)o*2048 + i];
    sq += (double)gpart[(size_t)(128+o)*2048 + i];
  }
  __shared__ double ds[256], dq[256];
  ds[t] = s; dq[t] = sq; __syncthreads();
  for (int off = 128; off > 0; off >>= 1){
    if (t < off){ ds[t] += ds[t+off]; dq[t] += dq[t+off]; }
    __syncthreads();
  }
  if (t == 0){
    double mu = ds[0] / (double)NTOT;
    double var = dq[0] / (double)NTOT - mu*mu;
    float A = g[o] / sqrtf((float)var + 1e-5f);
    float Cc = be[o] - (float)mu * A;
    params[o] = A; params[128+o] = Cc;
  }
}

// ---------------- K6: GEMM chain -> conv3 -> stats3 + per-m max/min over k ----------------
__global__ __launch_bounds__(256,1) void k_conv3(const float* __restrict__ pts_t,
    const float4* __restrict__ xyzn, const float* __restrict__ newxyz,
    const int* __restrict__ idx, const float* __restrict__ W1, const float* __restrict__ W2,
    const float* __restrict__ W3, const float* __restrict__ params1,
    const float* __restrict__ params2, float* __restrict__ gpart,
    float* __restrict__ zmax, float* __restrict__ zmin){
  __shared__ float s_w1[67*64];
  __shared__ float s_w2[64*64];
  __shared__ float s_w3[64*128];              // [c][o]
  __shared__ float s_p[256];
  __shared__ float s_x[67*XST];               // X1 -> h1 -> h2
  __shared__ float s_sm[8*128*2];
  int tid = threadIdx.x;
  for (int i = tid; i < 67*64; i += 256){ int c = i>>6, o = i&63; s_w1[i] = W1[o*67 + c]; }
  for (int i = tid; i < 64*64; i += 256){ int c = i>>6, o = i&63; s_w2[i] = W2[o*64 + c]; }
  for (int i = tid; i < 64*128; i += 256){ int c = i>>7, o = i&127; s_w3[c*128+o] = W3[o*64 + c]; }
  if (tid < 64){
    s_p[tid]      = params1[tid];     s_p[64+tid]  = params1[128+tid];
    s_p[128+tid]  = params2[tid];     s_p[192+tid] = params2[128+tid];
  }
  int bid = blockIdx.x, b = bid >> 8, m0 = (bid & 255) << 3;
  const float* nb = newxyz + (size_t)b*3*MM;
  gather_col(s_x, pts_t, xyzn, nb, idx, b, bid, tid);
  __syncthreads();
  int oq = tid & 7, pg = tid >> 3;
  int ob8 = oq*8, pb = pg*8;
  v2f acc[8][4];
  zero_acc(acc);
  for (int c = 0; c < 67; ++c) gemm_step(acc, s_w1, s_x, c, ob8, pb);
  bnrelu_tile(acc, s_p, s_p+64, ob8);
  __syncthreads();
  stash_tile(acc, s_x, ob8, pb);              // h1
  __syncthreads();
  zero_acc(acc);
  for (int c = 0; c < 64; ++c) gemm_step(acc, s_w2, s_x, c, ob8, pb);
  bnrelu_tile(acc, s_p+128, s_p+192, ob8);
  __syncthreads();
  stash_tile(acc, s_x, ob8, pb);              // h2
  __syncthreads();
  // phase3: conv3 GEMM; thread = (ml in 8, og in 32): o = og*4..+3, one m, all 32 k
  int ml = tid >> 5, og = tid & 31;
  v2f accK[4][16];
  #pragma unroll
  for (int oo = 0; oo < 4; ++oo)
    #pragma unroll
    for (int p = 0; p < 16; ++p) accK[oo][p] = (v2f){0.f, 0.f};
  for (int c = 0; c < 64; ++c){
    float4 w = *(const float4*)&s_w3[c*128 + og*4];
    v2f w0 = (v2f){w.x,w.x}, w1 = (v2f){w.y,w.y};
    v2f w2 = (v2f){w.z,w.z}, w3v = (v2f){w.w,w.w};
    #pragma unroll
    for (int q = 0; q < 8; ++q){
      float4 xv = *(const float4*)&s_x[c*XST + ml*32 + q*4];   // broadcast per ml
      v2f xa = (v2f){xv.x, xv.y}, xb2 = (v2f){xv.z, xv.w};
      accK[0][2*q]   = __builtin_elementwise_fma(w0,  xa,  accK[0][2*q]);
      accK[0][2*q+1] = __builtin_elementwise_fma(w0,  xb2, accK[0][2*q+1]);
      accK[1][2*q]   = __builtin_elementwise_fma(w1,  xa,  accK[1][2*q]);
      accK[1][2*q+1] = __builtin_elementwise_fma(w1,  xb2, accK[1][2*q+1]);
      accK[2][2*q]   = __builtin_elementwise_fma(w2,  xa,  accK[2][2*q]);
      accK[2][2*q+1] = __builtin_elementwise_fma(w2,  xb2, accK[2][2*q+1]);
      accK[3][2*q]   = __builtin_elementwise_fma(w3v, xa,  accK[3][2*q]);
      accK[3][2*q+1] = __builtin_elementwise_fma(w3v, xb2, accK[3][2*q+1]);
    }
  }
  int m = m0 + ml;
  #pragma unroll
  for (int oo = 0; oo < 4; ++oo){
    float mx = -3.4e38f, mn = 3.4e38f, s = 0.f, sq = 0.f;
    #pragma unroll
    for (int p = 0; p < 16; ++p){
      float v0 = accK[oo][p].x, v1 = accK[oo][p].y;
      mx = fmaxf(mx, v0); mx = fmaxf(mx, v1);
      mn = fminf(mn, v0); mn = fminf(mn, v1);
      s += v0; s += v1;
      sq = fmaf(v0, v0, sq); sq = fmaf(v1, v1, sq);
    }
    int o = og*4 + oo;
    zmax[((size_t)(b*128 + o))*MM + m] = mx;
    zmin[((size_t)(b*128 + o))*MM + m] = mn;
    s_sm[(ml*128+o)*2] = s; s_sm[(ml*128+o)*2+1] = sq;
  }
  __syncthreads();
  {
    int o = tid >> 1, st = tid & 1;
    float S = 0.f;
    #pragma unroll
    for (int mm = 0; mm < 8; ++mm) S += s_sm[(mm*128+o)*2 + st];
    gpart[(size_t)(st*128+o)*2048 + bid] = S;
  }
}

// ---------------- final output: bn3 affine on max/min, relu ----------------
__global__ __launch_bounds__(256) void k_out(const float* __restrict__ zmax,
    const float* __restrict__ zmin, const float* __restrict__ params3,
    float* __restrict__ out){
  int i = blockIdx.x*256 + threadIdx.x;   // 2,097,152
  int o = (i >> 11) & 127;
  float A = params3[o], Cc = params3[128+o];
  float v = (A >= 0.f) ? fmaf(A, zmax[i], Cc) : fmaf(A, zmin[i], Cc);
  out[49152 + i] = fmaxf(v, 0.f);
}

extern "C" void kernel_launch(void* const* d_in, const int* in_sizes, int n_in,
                              void* d_out, int out_size, void* d_ws, size_t ws_size,
                              hipStream_t stream){
  const float* xyz    = (const float*)d_in[0];
  const float* points = (const float*)d_in[1];
  const float* W1  = (const float*)d_in[2];
  const float* g1  = (const float*)d_in[4];
  const float* be1 = (const float*)d_in[5];
  const float* W2  = (const float*)d_in[6];
  const float* g2  = (const float*)d_in[8];
  const float* be2 = (const float*)d_in[9];
  const float* W3  = (const float*)d_in[10];
  const float* g3  = (const float*)d_in[12];
  const float* be3 = (const float*)d_in[13];

  if (ws_size < (size_t)WS_TOTAL * sizeof(float)) return;  // need ~42 MB scratch

  float*  ws     = (float*)d_ws;
  float*  pts_t  = ws + WS_PTS_T;
  float4* xyzn   = (float4*)(ws + WS_XYZN);
  int*    idx    = (int*)(ws + WS_IDX);
  float*  gpart  = ws + WS_GPART;
  float*  params = ws + WS_PARAMS;
  float*  zmax   = ws + WS_ZMAX;
  float*  zmin   = ws + WS_ZMIN;
  float*  out    = (float*)d_out;
  float*  newxyz = out;   // (B,3,M) at offset 0

  hipLaunchKernelGGL(k_fps,       dim3(8),    dim3(256), 0, stream, xyz, newxyz);
  hipLaunchKernelGGL(k_transpose, dim3(1024), dim3(256), 0, stream, points, pts_t);
  hipLaunchKernelGGL(k_xyzn,      dim3(256),  dim3(256), 0, stream, xyz, xyzn);
  hipLaunchKernelGGL(k_ballq,     dim3(512),  dim3(256), 0, stream, xyzn, newxyz, idx);
  hipLaunchKernelGGL(k_conv1_stats, dim3(2048), dim3(256), 0, stream,
                     pts_t, xyzn, newxyz, idx, W1, gpart);
  hipLaunchKernelGGL(k_bnfin, dim3(64), dim3(256), 0, stream, gpart, g1, be1, params+0);
  hipLaunchKernelGGL(k_conv2_stats, dim3(2048), dim3(256), 0, stream,
                     pts_t, xyzn, newxyz, idx, W1, W2, params+0, gpart);
  hipLaunchKernelGGL(k_bnfin, dim3(64), dim3(256), 0, stream, gpart, g2, be2, params+256);
  hipLaunchKernelGGL(k_conv3, dim3(2048), dim3(256), 0, stream,
                     pts_t, xyzn, newxyz, idx, W1, W2, W3, params+0, params+256,
                     gpart, zmax, zmin);
  hipLaunchKernelGGL(k_bnfin, dim3(128), dim3(256), 0, stream, gpart, g3, be3, params+512);
  hipLaunchKernelGGL(k_out, dim3(8192), dim3(256), 0, stream, zmax, zmin, params+512, out);
}

// Round 10
// 2567.817 us; speedup vs baseline: 1.0263x; 1.0263x over previous
//
#include <hip/hip_runtime.h>

#define BB 8
#define NN 8192
#define MM 2048
#define KK 32
#define NTOT (BB*MM*KK)   // 524288

// ws layout (float offsets)
#define WS_PTS_T  0          // 4,194,304 f  (B,N,64)
#define WS_XYZN   4194304    // 1,048,576 f  (B,N) float4
#define WS_IDX    5242880    //   524,288 i  (B,M,32)
#define WS_GPART  5767168    //   524,288 f  [s*128+o][2048]
#define WS_PARAMS 6291456    //     1,024 f  layer*256 + {A[0..127], C[128..255]}
#define WS_ZMAX   6292480    // 2,097,152 f
#define WS_ZMIN   8389632    // 2,097,152 f
#define WS_TOTAL  10486784

typedef float v2f __attribute__((ext_vector_type(2)));

// ---------------- transpose points (B,64,N) -> (B,N,64) ----------------
__global__ __launch_bounds__(256) void k_transpose(const float* __restrict__ pts,
                                                   float* __restrict__ pts_t){
  __shared__ float tile[64][65];
  int bid = blockIdx.x;
  int b = bid >> 7;                 // 128 tiles per batch
  int n0 = (bid & 127) << 6;
  int tx = threadIdx.x & 63, ty = threadIdx.x >> 6;
  const float* src = pts + (size_t)b*64*NN;
  #pragma unroll
  for (int c = ty; c < 64; c += 4)
    tile[c][tx] = src[(size_t)c*NN + n0 + tx];
  __syncthreads();
  float* dst = pts_t + ((size_t)b*NN + n0)*64;
  #pragma unroll
  for (int r = ty; r < 64; r += 4)
    dst[(size_t)r*64 + tx] = tile[tx][r];
}

// ---------------- xyz + norm staging (B,N) float4 ----------------
__global__ __launch_bounds__(256) void k_xyzn(const float* __restrict__ xyz,
                                              float4* __restrict__ xyzn){
  #pragma clang fp contract(off)
  int i = blockIdx.x*256 + threadIdx.x;   // 65536
  int b = i >> 13, n = i & 8191;
  const float* p = xyz + (size_t)b*3*NN;
  float x = p[n], y = p[NN+n], z = p[2*NN+n];
  float nrm = (x*x + y*y) + z*z;
  xyzn[i] = make_float4(x, y, z, nrm);
}

// ---------------- farthest point sampling (r8 version — measured 1800us) ----------------
#define DPPMAXF(ctrl, rmask)                                                 \
  {                                                                          \
    float s_ = __int_as_float(__builtin_amdgcn_update_dpp(                   \
        __float_as_int(m), __float_as_int(m), (ctrl), (rmask), 0xf, false)); \
    m = fmaxf(m, s_);                                                        \
  }

__global__ __launch_bounds__(256,1) void k_fps(const float* __restrict__ xyz,
                                               float* __restrict__ out_newxyz){
  #pragma clang fp contract(off)
  __shared__ float4 sp4[NN];                     // 128 KB
  __shared__ unsigned long long swk[2][4];
  int b = blockIdx.x, tid = threadIdx.x;
  const float* xb = xyz + (size_t)b*3*NN;
  int n0 = tid << 5;                             // 32 contiguous points
  v2f px[16], py[16], pz[16], dd[16];
  const float4* xb4 = (const float4*)xb;
  #pragma unroll
  for (int q = 0; q < 8; ++q){
    float4 X = xb4[(n0>>2) + q];
    float4 Y = xb4[(NN>>2) + (n0>>2) + q];
    float4 Z = xb4[((2*NN)>>2) + (n0>>2) + q];
    px[2*q]   = (v2f){X.x, X.y}; px[2*q+1] = (v2f){X.z, X.w};
    py[2*q]   = (v2f){Y.x, Y.y}; py[2*q+1] = (v2f){Y.z, Y.w};
    pz[2*q]   = (v2f){Z.x, Z.y}; pz[2*q+1] = (v2f){Z.z, Z.w};
    dd[2*q]   = (v2f){1e10f,1e10f}; dd[2*q+1] = (v2f){1e10f,1e10f};
    sp4[n0+4*q+0] = make_float4(X.x, Y.x, Z.x, 0.f);
    sp4[n0+4*q+1] = make_float4(X.y, Y.y, Z.y, 0.f);
    sp4[n0+4*q+2] = make_float4(X.z, Y.z, Z.z, 0.f);
    sp4[n0+4*q+3] = make_float4(X.w, Y.w, Z.w, 0.f);
  }
  __syncthreads();
  float4 c0 = sp4[0];                            // far = 0 initially
  float cx = c0.x, cy = c0.y, cz = c0.z;
  float* ob = out_newxyz + (size_t)b*3*MM;
  int lane = tid & 63, wid = tid >> 6;
  for (int s = 0; s < 8; ++s){
    float ox = 0.f, oy = 0.f, oz = 0.f;
    #pragma unroll 1
    for (int ti = 0; ti < 256; ++ti){
      if (tid == ti){ ox = cx; oy = cy; oz = cz; }   // register capture
      v2f cvx = (v2f){cx,cx}, cvy = (v2f){cy,cy}, cvz = (v2f){cz,cz};
      v2f bv2 = (v2f){-1.f,-1.f};
      #pragma unroll
      for (int g = 0; g < 16; ++g){
        v2f dx = px[g]-cvx, dy = py[g]-cvy, dz = pz[g]-cvz;
        v2f xx = dx*dx, yy = dy*dy, zz = dz*dz;
        v2f sm = xx + yy;                           // linear sum order == np
        v2f d  = sm + zz;
        v2f nd = __builtin_elementwise_min(dd[g], d);
        dd[g] = nd;
        bv2 = __builtin_elementwise_max(bv2, nd);
      }
      float bv = fmaxf(bv2.x, bv2.y);
      float m = bv;
      DPPMAXF(0x111, 0xf)   // row_shr:1
      DPPMAXF(0x112, 0xf)   // row_shr:2
      DPPMAXF(0x114, 0xf)   // row_shr:4
      DPPMAXF(0x118, 0xf)   // row_shr:8
      DPPMAXF(0x142, 0xa)   // row_bcast:15 -> rows 1,3
      DPPMAXF(0x143, 0xc)   // row_bcast:31 -> rows 2,3
      float wm = __int_as_float(__builtin_amdgcn_readlane(__float_as_int(m), 63));
      unsigned long long msk = __ballot(bv == wm);
      int wl = (int)__builtin_ctzll(msk);           // lowest lane among ties
      int bj = 0;
      #pragma unroll
      for (int g = 15; g >= 0; --g){                // descending: last match = lowest j
        if (dd[g].y == bv) bj = 2*g+1;
        if (dd[g].x == bv) bj = 2*g;
      }
      int nwin = __builtin_amdgcn_readlane(n0 + bj, wl);
      int buf = ti & 1;
      if (lane == 0){
        unsigned long long key =
            ((unsigned long long)__float_as_uint(wm) << 32) |
            (unsigned int)(~(unsigned int)nwin);
        swk[buf][wid] = key;
      }
      __syncthreads();
      const unsigned long long* kk = swk[buf];
      unsigned long long k0=kk[0], k1=kk[1], k2=kk[2], k3=kk[3];
      unsigned long long a = (k0>k1)?k0:k1, c2 = (k2>k3)?k2:k3;
      unsigned long long kmax = (a>c2)?a:c2;
      int far = (int)(~(unsigned int)kmax) & (NN-1);
      float4 c4 = sp4[far];
      cx = c4.x; cy = c4.y; cz = c4.z;
    }
    ob[(s<<8)+tid] = ox; ob[MM+(s<<8)+tid] = oy; ob[2*MM+(s<<8)+tid] = oz;
  }
}

// ---------------- ball query: parallel mask build + serial emit ----------------
__global__ __launch_bounds__(256) void k_ballq(const float4* __restrict__ xyzn,
                                               const float* __restrict__ newxyz,
                                               int* __restrict__ idx){
  #pragma clang fp contract(off)
  __shared__ unsigned long long s_mask[32][129];   // padded: 2-way bank alias only
  __shared__ float4 s_c4[32];
  const float R2 = (float)(0.2*0.2);
  int b = blockIdx.x >> 6;                 // 64 blocks per batch
  int m0 = (blockIdx.x & 63) << 5;         // 32 centroids per block
  int tid = threadIdx.x, lane = tid & 63, wv = tid >> 6;
  const float* nb = newxyz + (size_t)b*3*MM;
  if (tid < 32){
    int m = m0 + tid;
    float cx = nb[m], cy = nb[MM+m], cz = nb[2*MM+m];
    float cn = (cx*cx + cy*cy) + cz*cz;
    s_c4[tid] = make_float4(cx, cy, cz, cn);
  }
  __syncthreads();
  const float4* src = xyzn + (size_t)b*NN;
  for (int ci = 0; ci < 32; ++ci){
    int ch = ci*4 + wv;
    float4 p = src[ch*64 + lane];
    #pragma unroll 8
    for (int mi = 0; mi < 32; ++mi){
      float4 c = s_c4[mi];
      float dot = (c.x*p.x + c.y*p.y) + c.z*p.z;   // linear, no fma (matches np)
      float sq = (c.w + p.w) - 2.0f*dot;
      unsigned long long mk = __ballot(sq < R2);
      if (lane == 0) s_mask[mi][ch] = mk;
    }
  }
  __syncthreads();
  if (tid < 32){
    int m = m0 + tid;
    int* om = idx + ((size_t)(b*MM + m))*KK;
    int filled = 0, first = -1;
    for (int ch = 0; ch < 128 && filled < KK; ++ch){
      unsigned long long mk = s_mask[tid][ch];
      while (mk){
        int bp = __builtin_ctzll(mk);
        mk &= mk - 1;
        int j = ch*64 + bp;
        if (first < 0) first = j;
        om[filled++] = j;
        if (filled == KK) break;
      }
    }
    int pad = (first < 0) ? 0 : first;
    for (int s = filled; s < KK; ++s) om[s] = pad;
  }
}

// ---------------- GEMM helpers: 512-thread conv blocks (2 waves/SIMD) ----------------
// Thread owns 8 outs x 4 positions. oq = tid&7 (ob8 = oq*8), pg = tid>>3 (pb = pg*4).
#define XST 260    // X_lds row stride in floats
#define PSTW 130   // s_pp row stride for 64-group stats (2-way bank alias, free)

// one K-step: acc[8 outs][2 v2f = 4 pos] += w (x) x
__device__ __forceinline__ void gemm_step(v2f (&acc)[8][2], const float* sw,
                                          const float* sx, int c, int ob8, int pb){
  float4 X = *(const float4*)&sx[c*XST + pb];
  v2f x0 = (v2f){X.x, X.y}, x1 = (v2f){X.z, X.w};
  float4 W0 = *(const float4*)&sw[c*64 + ob8];
  float4 W1 = *(const float4*)&sw[c*64 + ob8 + 4];
  float ws[8] = {W0.x,W0.y,W0.z,W0.w,W1.x,W1.y,W1.z,W1.w};
  #pragma unroll
  for (int oi = 0; oi < 8; ++oi){
    v2f wv = (v2f){ws[oi], ws[oi]};
    acc[oi][0] = __builtin_elementwise_fma(wv, x0, acc[oi][0]);
    acc[oi][1] = __builtin_elementwise_fma(wv, x1, acc[oi][1]);
  }
}

__device__ __forceinline__ void zero_acc(v2f (&acc)[8][2]){
  #pragma unroll
  for (int oi = 0; oi < 8; ++oi){ acc[oi][0] = (v2f){0.f,0.f}; acc[oi][1] = (v2f){0.f,0.f}; }
}

// gather: 512 threads, thread pair (pos, pos+256) splits the 67 channels
__device__ __forceinline__ void gather_col(float* sx, const float* pts_t,
    const float4* xyzn, const float* nb, const int* idx, int b, int bid, int tid){
  int pos = tid & 255, half = tid >> 8;
  int m0 = (bid & 255) << 3;
  int m = m0 + (pos >> 5), k = pos & 31;
  int j = idx[((size_t)(b*MM + m))*KK + k];
  const float4* pf = (const float4*)(pts_t + ((size_t)b*NN + j)*64);
  if (half == 0){
    float4 P = xyzn[(size_t)b*NN + j];
    sx[0*XST + pos] = P.x - nb[m];
    sx[1*XST + pos] = P.y - nb[MM+m];
    sx[2*XST + pos] = P.z - nb[2*MM+m];
    #pragma unroll
    for (int c4 = 0; c4 < 8; ++c4){
      float4 v = pf[c4];
      sx[(3+4*c4+0)*XST + pos] = v.x;
      sx[(3+4*c4+1)*XST + pos] = v.y;
      sx[(3+4*c4+2)*XST + pos] = v.z;
      sx[(3+4*c4+3)*XST + pos] = v.w;
    }
  } else {
    #pragma unroll
    for (int c4 = 8; c4 < 16; ++c4){
      float4 v = pf[c4];
      sx[(3+4*c4+0)*XST + pos] = v.x;
      sx[(3+4*c4+1)*XST + pos] = v.y;
      sx[(3+4*c4+2)*XST + pos] = v.z;
      sx[(3+4*c4+3)*XST + pos] = v.w;
    }
  }
}

__device__ __forceinline__ void bnrelu_tile(v2f (&acc)[8][2], const float* sA,
                                            const float* sC, int ob8){
  v2f Z = (v2f){0.f, 0.f};
  #pragma unroll
  for (int oi = 0; oi < 8; ++oi){
    v2f Av = (v2f){sA[ob8+oi], sA[ob8+oi]};
    v2f Cv = (v2f){sC[ob8+oi], sC[ob8+oi]};
    acc[oi][0] = __builtin_elementwise_max(__builtin_elementwise_fma(Av, acc[oi][0], Cv), Z);
    acc[oi][1] = __builtin_elementwise_max(__builtin_elementwise_fma(Av, acc[oi][1], Cv), Z);
  }
}

__device__ __forceinline__ void stash_tile(const v2f (&acc)[8][2], float* sx,
                                           int ob8, int pb){
  #pragma unroll
  for (int oi = 0; oi < 8; ++oi)
    *(float4*)&sx[(ob8+oi)*XST + pb] =
        make_float4(acc[oi][0].x, acc[oi][0].y, acc[oi][1].x, acc[oi][1].y);
}

// per-thread 4-pos stats -> s_pp[o*PSTW + pg*2 + st] -> gpart (deterministic)
__device__ __forceinline__ void tile_stats(const v2f (&acc)[8][2], float* s_pp,
    float* gpart, int ob8, int pg, int tid, int bid){
  #pragma unroll
  for (int oi = 0; oi < 8; ++oi){
    v2f a0 = acc[oi][0], a1 = acc[oi][1];
    float s  = (a0.x + a0.y) + (a1.x + a1.y);
    float q2 = (a0.x*a0.x + a0.y*a0.y) + (a1.x*a1.x + a1.y*a1.y);
    int o = ob8 + oi;
    s_pp[o*PSTW + pg*2 + 0] = s;
    s_pp[o*PSTW + pg*2 + 1] = q2;
  }
  __syncthreads();
  if (tid < 128){
    int o = tid >> 1, st = tid & 1;
    float S = 0.f;
    #pragma unroll 8
    for (int q = 0; q < 64; ++q) S += s_pp[o*PSTW + q*2 + st];
    gpart[(size_t)(st*128 + o)*2048 + bid] = S;
  }
}

// ---------------- K4: conv1 (GEMM) -> stats1 ----------------
__global__ __launch_bounds__(512,1) void k_conv1_stats(const float* __restrict__ pts_t,
    const float4* __restrict__ xyzn, const float* __restrict__ newxyz,
    const int* __restrict__ idx, const float* __restrict__ W1, float* __restrict__ gpart){
  __shared__ float s_w1[67*64];
  __shared__ float s_x[67*XST];               // also reused as s_pp
  int tid = threadIdx.x;
  for (int i = tid; i < 67*64; i += 512){ int c = i>>6, o = i&63; s_w1[i] = W1[o*67 + c]; }
  int bid = blockIdx.x, b = bid >> 8;
  const float* nb = newxyz + (size_t)b*3*MM;
  gather_col(s_x, pts_t, xyzn, nb, idx, b, bid, tid);
  __syncthreads();
  int oq = tid & 7, pg = tid >> 3;
  int ob8 = oq*8, pb = pg*4;
  v2f acc[8][2];
  zero_acc(acc);
  for (int c = 0; c < 67; ++c) gemm_step(acc, s_w1, s_x, c, ob8, pb);
  __syncthreads();                            // s_x dead -> reuse
  tile_stats(acc, s_x, gpart, ob8, pg, tid, bid);
}

// ---------------- K5: conv1 -> bn1/relu -> conv2 (GEMM) -> stats2 ----------------
__global__ __launch_bounds__(512,1) void k_conv2_stats(const float* __restrict__ pts_t,
    const float4* __restrict__ xyzn, const float* __restrict__ newxyz,
    const int* __restrict__ idx, const float* __restrict__ W1, const float* __restrict__ W2,
    const float* __restrict__ params1, float* __restrict__ gpart){
  __shared__ float s_w1[67*64];
  __shared__ float s_w2[64*64];
  __shared__ float s_p[128];
  __shared__ float s_x[67*XST];               // X1, then h1 stash, then s_pp
  int tid = threadIdx.x;
  for (int i = tid; i < 67*64; i += 512){ int c = i>>6, o = i&63; s_w1[i] = W1[o*67 + c]; }
  for (int i = tid; i < 64*64; i += 512){ int c = i>>6, o = i&63; s_w2[i] = W2[o*64 + c]; }
  if (tid < 64){ s_p[tid] = params1[tid]; s_p[64+tid] = params1[128+tid]; }
  int bid = blockIdx.x, b = bid >> 8;
  const float* nb = newxyz + (size_t)b*3*MM;
  gather_col(s_x, pts_t, xyzn, nb, idx, b, bid, tid);
  __syncthreads();
  int oq = tid & 7, pg = tid >> 3;
  int ob8 = oq*8, pb = pg*4;
  v2f acc[8][2];
  zero_acc(acc);
  for (int c = 0; c < 67; ++c) gemm_step(acc, s_w1, s_x, c, ob8, pb);
  bnrelu_tile(acc, s_p, s_p+64, ob8);
  __syncthreads();                            // everyone done reading X1
  stash_tile(acc, s_x, ob8, pb);
  __syncthreads();
  zero_acc(acc);
  for (int c = 0; c < 64; ++c) gemm_step(acc, s_w2, s_x, c, ob8, pb);
  __syncthreads();                            // h1 dead -> reuse as s_pp
  tile_stats(acc, s_x, gpart, ob8, pg, tid, bid);
}

// ---------------- BN finalize: deterministic f64 reduce ----------------
__global__ __launch_bounds__(256) void k_bnfin(const float* __restrict__ gpart,
    const float* __restrict__ g, const float* __restrict__ be, float* __restrict__ params){
  int o = blockIdx.x, t = threadIdx.x;
  double s = 0.0, sq = 0.0;
  for (int i = t; i < 2048; i += 256){
    s  += (double)gpart[(size_t)o*2048 + i];
    sq += (double)gpart[(size_t)(128+o)*2048 + i];
  }
  __shared__ double ds[256], dq[256];
  ds[t] = s; dq[t] = sq; __syncthreads();
  for (int off = 128; off > 0; off >>= 1){
    if (t < off){ ds[t] += ds[t+off]; dq[t] += dq[t+off]; }
    __syncthreads();
  }
  if (t == 0){
    double mu = ds[0] / (double)NTOT;
    double var = dq[0] / (double)NTOT - mu*mu;
    float A = g[o] / sqrtf((float)var + 1e-5f);
    float Cc = be[o] - (float)mu * A;
    params[o] = A; params[128+o] = Cc;
  }
}

// ---------------- K6: GEMM chain -> conv3 -> stats3 + per-m max/min over k ----------------
__global__ __launch_bounds__(512,1) void k_conv3(const float* __restrict__ pts_t,
    const float4* __restrict__ xyzn, const float* __restrict__ newxyz,
    const int* __restrict__ idx, const float* __restrict__ W1, const float* __restrict__ W2,
    const float* __restrict__ W3, const float* __restrict__ params1,
    const float* __restrict__ params2, float* __restrict__ gpart,
    float* __restrict__ zmax, float* __restrict__ zmin){
  __shared__ float s_w1[67*64];
  __shared__ float s_w2[64*64];
  __shared__ float s_w3[64*128];              // [c][o]
  __shared__ float s_p[256];
  __shared__ float s_x[67*XST];               // X1 -> h1 -> h2
  __shared__ float s_sm[8*128*2];
  int tid = threadIdx.x;
  for (int i = tid; i < 67*64; i += 512){ int c = i>>6, o = i&63; s_w1[i] = W1[o*67 + c]; }
  for (int i = tid; i < 64*64; i += 512){ int c = i>>6, o = i&63; s_w2[i] = W2[o*64 + c]; }
  for (int i = tid; i < 64*128; i += 512){ int c = i>>7, o = i&127; s_w3[c*128+o] = W3[o*64 + c]; }
  if (tid < 64){
    s_p[tid]      = params1[tid];     s_p[64+tid]  = params1[128+tid];
    s_p[128+tid]  = params2[tid];     s_p[192+tid] = params2[128+tid];
  }
  int bid = blockIdx.x, b = bid >> 8, m0 = (bid & 255) << 3;
  const float* nb = newxyz + (size_t)b*3*MM;
  gather_col(s_x, pts_t, xyzn, nb, idx, b, bid, tid);
  __syncthreads();
  int oq = tid & 7, pg = tid >> 3;
  int ob8 = oq*8, pb = pg*4;
  v2f acc[8][2];
  zero_acc(acc);
  for (int c = 0; c < 67; ++c) gemm_step(acc, s_w1, s_x, c, ob8, pb);
  bnrelu_tile(acc, s_p, s_p+64, ob8);
  __syncthreads();
  stash_tile(acc, s_x, ob8, pb);              // h1
  __syncthreads();
  zero_acc(acc);
  for (int c = 0; c < 64; ++c) gemm_step(acc, s_w2, s_x, c, ob8, pb);
  bnrelu_tile(acc, s_p+128, s_p+192, ob8);
  __syncthreads();
  stash_tile(acc, s_x, ob8, pb);              // h2
  __syncthreads();
  // phase3: thread = (ml in 8, og in 64): o = og*2, og*2+1; one m, all 32 k
  int ml = tid >> 6, og = tid & 63;
  v2f accK[2][16];
  #pragma unroll
  for (int oo = 0; oo < 2; ++oo)
    #pragma unroll
    for (int p = 0; p < 16; ++p) accK[oo][p] = (v2f){0.f, 0.f};
  for (int c = 0; c < 64; ++c){
    v2f w = *(const v2f*)&s_w3[c*128 + og*2];
    v2f w0 = (v2f){w.x, w.x}, w1 = (v2f){w.y, w.y};
    #pragma unroll
    for (int q = 0; q < 8; ++q){
      float4 xv = *(const float4*)&s_x[c*XST + ml*32 + q*4];   // broadcast per ml
      v2f xa = (v2f){xv.x, xv.y}, xb2 = (v2f){xv.z, xv.w};
      accK[0][2*q]   = __builtin_elementwise_fma(w0, xa,  accK[0][2*q]);
      accK[0][2*q+1] = __builtin_elementwise_fma(w0, xb2, accK[0][2*q+1]);
      accK[1][2*q]   = __builtin_elementwise_fma(w1, xa,  accK[1][2*q]);
      accK[1][2*q+1] = __builtin_elementwise_fma(w1, xb2, accK[1][2*q+1]);
    }
  }
  int m = m0 + ml;
  #pragma unroll
  for (int oo = 0; oo < 2; ++oo){
    float mx = -3.4e38f, mn = 3.4e38f, s = 0.f, sq = 0.f;
    #pragma unroll
    for (int p = 0; p < 16; ++p){
      float v0 = accK[oo][p].x, v1 = accK[oo][p].y;
      mx = fmaxf(mx, v0); mx = fmaxf(mx, v1);
      mn = fminf(mn, v0); mn = fminf(mn, v1);
      s += v0; s += v1;
      sq = fmaf(v0, v0, sq); sq = fmaf(v1, v1, sq);
    }
    int o = og*2 + oo;
    zmax[((size_t)(b*128 + o))*MM + m] = mx;
    zmin[((size_t)(b*128 + o))*MM + m] = mn;
    s_sm[(ml*128+o)*2] = s; s_sm[(ml*128+o)*2+1] = sq;
  }
  __syncthreads();
  if (tid < 256){
    int o = tid >> 1, st = tid & 1;
    float S = 0.f;
    #pragma unroll
    for (int mm = 0; mm < 8; ++mm) S += s_sm[(mm*128+o)*2 + st];
    gpart[(size_t)(st*128+o)*2048 + bid] = S;
  }
}

// ---------------- final output: bn3 affine on max/min, relu ----------------
__global__ __launch_bounds__(256) void k_out(const float* __restrict__ zmax,
    const float* __restrict__ zmin, const float* __restrict__ params3,
    float* __restrict__ out){
  int i = blockIdx.x*256 + threadIdx.x;   // 2,097,152
  int o = (i >> 11) & 127;
  float A = params3[o], Cc = params3[128+o];
  float v = (A >= 0.f) ? fmaf(A, zmax[i], Cc) : fmaf(A, zmin[i], Cc);
  out[49152 + i] = fmaxf(v, 0.f);
}

extern "C" void kernel_launch(void* const* d_in, const int* in_sizes, int n_in,
                              void* d_out, int out_size, void* d_ws, size_t ws_size,
                              hipStream_t stream){
  const float* xyz    = (const float*)d_in[0];
  const float* points = (const float*)d_in[1];
  const float* W1  = (const float*)d_in[2];
  const float* g1  = (const float*)d_in[4];
  const float* be1 = (const float*)d_in[5];
  const float* W2  = (const float*)d_in[6];
  const float* g2  = (const float*)d_in[8];
  const float* be2 = (const float*)d_in[9];
  const float* W3  = (const float*)d_in[10];
  const float* g3  = (const float*)d_in[12];
  const float* be3 = (const float*)d_in[13];

  if (ws_size < (size_t)WS_TOTAL * sizeof(float)) return;  // need ~42 MB scratch

  float*  ws     = (float*)d_ws;
  float*  pts_t  = ws + WS_PTS_T;
  float4* xyzn   = (float4*)(ws + WS_XYZN);
  int*    idx    = (int*)(ws + WS_IDX);
  float*  gpart  = ws + WS_GPART;
  float*  params = ws + WS_PARAMS;
  float*  zmax   = ws + WS_ZMAX;
  float*  zmin   = ws + WS_ZMIN;
  float*  out    = (float*)d_out;
  float*  newxyz = out;   // (B,3,M) at offset 0

  hipLaunchKernelGGL(k_fps,       dim3(8),    dim3(256), 0, stream, xyz, newxyz);
  hipLaunchKernelGGL(k_transpose, dim3(1024), dim3(256), 0, stream, points, pts_t);
  hipLaunchKernelGGL(k_xyzn,      dim3(256),  dim3(256), 0, stream, xyz, xyzn);
  hipLaunchKernelGGL(k_ballq,     dim3(512),  dim3(256), 0, stream, xyzn, newxyz, idx);
  hipLaunchKernelGGL(k_conv1_stats, dim3(2048), dim3(512), 0, stream,
                     pts_t, xyzn, newxyz, idx, W1, gpart);
  hipLaunchKernelGGL(k_bnfin, dim3(64), dim3(256), 0, stream, gpart, g1, be1, params+0);
  hipLaunchKernelGGL(k_conv2_stats, dim3(2048), dim3(512), 0, stream,
                     pts_t, xyzn, newxyz, idx, W1, W2, params+0, gpart);
  hipLaunchKernelGGL(k_bnfin, dim3(64), dim3(256), 0, stream, gpart, g2, be2, params+256);
  hipLaunchKernelGGL(k_conv3, dim3(2048), dim3(512), 0, stream,
                     pts_t, xyzn, newxyz, idx, W1, W2, W3, params+0, params+256,
                     gpart, zmax, zmin);
  hipLaunchKernelGGL(k_bnfin, dim3(128), dim3(256), 0, stream, gpart, g3, be3, params+512);
  hipLaunchKernelGGL(k_out, dim3(8192), dim3(256), 0, stream, zmax, zmin, params+512, out);
}